// Round 11
// baseline (2223.913 us; speedup 1.0000x reference)
//
#include <hip/hip_runtime.h>

#define NS   16384
#define NIN  16384
#define CIN  128
#define COUT 128
#define KNB  9
#define MCH  66              // 64 MLP channels + 1 (b3 ones) + 1 zero pad
#define QDIM (CIN*MCH)       // 8448, q = m*128 + j (j-fastest)
#define W0C  30.0f

typedef __bf16 bf16;
typedef bf16  bf16x8  __attribute__((ext_vector_type(8)));
typedef bf16  bf16x2  __attribute__((ext_vector_type(2)));
typedef _Float16 f16;
typedef f16   f16x2   __attribute__((ext_vector_type(2)));
typedef unsigned short u16;
typedef u16   u16x8   __attribute__((ext_vector_type(8)));
typedef float floatx4 __attribute__((ext_vector_type(4)));
typedef unsigned int u32;

__device__ inline u16 f2bf(float f){
  u32 u = __float_as_uint(f);
  u += 0x7fffu + ((u >> 16) & 1u);   // round-to-nearest-even
  return (u16)(u >> 16);
}
__device__ inline float bf2f(u16 s){
  return __uint_as_float((u32)s << 16);
}
__device__ inline u16 f2h(float f){
  f16 h = (f16)f; return __builtin_bit_cast(u16, h);
}
// 1-instr packed f32->2xbf16 (RNE), gfx950-verified instruction
__device__ inline u32 cvtpk2(float lo, float hi){
  u32 r; asm("v_cvt_pk_bf16_f32 %0, %1, %2" : "=v"(r) : "v"(lo), "v"(hi)); return r;
}

// ---- build-operand format selection (r10 note: __builtin_amdgcn_fdot2 did NOT
// pass __has_builtin on this toolchain — counters were bit-identical to bf16
// fallback; the guards below keep the safe fallback behavior) ----
#if defined(__has_builtin)
# if __has_builtin(__builtin_amdgcn_fdot2)
#  define XFMT_F16 1
# endif
# if __has_builtin(__builtin_amdgcn_fdot2_f32_bf16)
#  define HAVE_BF16DOT 1
# endif
#endif
#ifndef XFMT_F16
# define XFMT_F16 0
#endif
#ifndef HAVE_BF16DOT
# define HAVE_BF16DOT 0
#endif

#if XFMT_F16
# define F2X(f)  f2h(f)
# define X_ONE   0x3C00u
#else
# define F2X(f)  f2bf(f)
# define X_ONE   0x3F80u
#endif

// dot over a packed k-pair in X-format: x.lo*h.lo + x.hi*h.hi + c (f32 accum)
__device__ inline float dot2x(u32 x2, u32 h2, float c){
#if XFMT_F16
  return __builtin_amdgcn_fdot2(__builtin_bit_cast(f16x2, x2),
                                __builtin_bit_cast(f16x2, h2), c, false);
#elif HAVE_BF16DOT
  return __builtin_amdgcn_fdot2_f32_bf16(__builtin_bit_cast(bf16x2, x2),
                                         __builtin_bit_cast(bf16x2, h2), c, false);
#else
  float xl = bf2f((u16)(x2 & 0xffffu)), xh = bf2f((u16)(x2 >> 16));
  float hl = bf2f((u16)(h2 & 0xffffu)), hh = bf2f((u16)(h2 >> 16));
  return fmaf(xh, hh, fmaf(xl, hl, c));
#endif
}

// barrier that orders LDS only — does NOT drain vmcnt, so global prefetches
// stay in flight across it (exact form used by the five-times-verified k_fused)
#define WG_BARRIER() do { \
  asm volatile("s_waitcnt lgkmcnt(0)" ::: "memory"); \
  __builtin_amdgcn_s_barrier(); \
} while (0)

// ---------------- K_prep: grid-partitioned fusion of k1h | k_tr | k0_vt ----------
#define PREP_K1H  (NS/32)                 // 512
#define PREP_KTR  2048                    // 8192 tiles / 4 per block
#define PREP_K0   ((COUT*QDIM + 1023)/1024)  // 1056
__global__ __launch_bounds__(1024) void k_prep(
      const float* __restrict__ coords,
      const float* __restrict__ W1, const float* __restrict__ b1,
      const float* __restrict__ W2, const float* __restrict__ b2,
      const float* __restrict__ x,
      const float* __restrict__ W3, const float* __restrict__ b3,
      u32* __restrict__ hK, u16* __restrict__ xT, u16* __restrict__ Vt){
  __shared__ u16 sh[KNB][32][66];              // 38,016 B (k1h role)
  __shared__ __align__(16) float tfl[4][32][33]; // 16,896 B (k_tr role)
  const int bid = blockIdx.x;
  const int tid = threadIdx.x;

  if (bid < PREP_K1H){
    // ---------------- k1h role ----------------
    const int lane = tid & 63;
    const int w    = tid >> 6;         // 0..15
    const int l0   = bid*32;
    for (int e = w; e < KNB*32; e += 16){
      int k = e >> 5, l = e & 31;
      int pt = (k << 14) + l0 + l;
      float c0 = coords[2*pt], c1 = coords[2*pt+1];
      float z  = fmaf(c0, W1[lane], fmaf(c1, W1[64+lane], b1[lane]));
      float h1 = sinf(W0C * z);
      float acc = b2[lane];
      #pragma unroll
      for (int mp = 0; mp < 64; ++mp)
        acc = fmaf(__shfl(h1, mp, 64), W2[mp*64 + lane], acc);
      sh[k][l][lane] = F2X(sinf(acc));
      if (lane == 0){ sh[k][l][64] = X_ONE; sh[k][l][65] = 0; }  // 1.0, 0.0
    }
    __syncthreads();
    for (int e = tid; e < 66*5*32; e += 1024){
      int m  = e / 160;
      int r  = e - m*160;
      int kp = r >> 5;
      int l  = r & 31;
      u32 lo = sh[2*kp][l][m];
      u32 hi = (kp < 4) ? (u32)sh[2*kp+1][l][m] : 0u;
      hK[(((size_t)m*5 + kp) << 14) + l0 + l] = lo | (hi << 16);
    }
  } else if (bid < PREP_K1H + PREP_KTR){
    // ---------------- k_tr role: 4 tiles of 32x32 per block ----------------
    const int sub = tid >> 8;          // 0..3 : which tile
    const int tx  = tid & 31;
    const int ty  = (tid >> 5) & 7;
    const int t   = (bid - PREP_K1H)*4 + sub;   // 0..8191
    const int p0  = (t & 511) * 32;             // NIN/32 = 512
    const int j0  = ((t >> 9) & 3) * 32;        // CIN/32 = 4
    const int b   = t >> 11;                    // 4
    const float* xb  = x  + (size_t)b*CIN*NIN;
    u16*         xTb = xT + (size_t)b*NIN*CIN;
    #pragma unroll
    for (int n = 0; n < 4; ++n)
      tfl[sub][ty+8*n][tx] = xb[(size_t)(j0+ty+8*n)*NIN + p0+tx];
    __syncthreads();
    #pragma unroll
    for (int n = 0; n < 4; ++n)
      xTb[(size_t)(p0+ty+8*n)*CIN + j0+tx] = F2X(tfl[sub][tx][ty+8*n]);
  } else {
    // ---------------- k0_vt role (bf16 — feeds MFMA B directly) ----------------
    int idx = (bid - PREP_K1H - PREP_KTR)*1024 + tid;
    if (idx < COUT*QDIM){
      int i = idx / QDIM;
      int q = idx - i*QDIM;
      int m = q >> 7;
      int j = q & 127;
      float v = 0.f;
      if (m < 64)       v = W3[m*16384 + i*128 + j];
      else if (m == 64) v = b3[i*128 + j];
      Vt[idx] = f2bf(v);
    }
  }
}

// ---------------- K_fused: r3-verified structure; SINGLE CHANGE vs r10: ----------
// __launch_bounds__(512, 6) — ask allocator for <=85 regs -> 6 waves/SIMD ->
// 3 blocks/CU (24 waves, +50% TLP over the register-capped 2 blocks).
// All pipes <=30% busy across r3/r5/r8/r9/r10 => latency-bound, TLP-starved;
// every within-schedule lever (traffic, barriers, roles, VALU) was flat.
// Spill victims should be the cold 1-use-per-mg temporaries (hra/hrb/bv),
// not the hot xp (80 uses/mg). Directive is correctness-neutral.
__global__ __launch_bounds__(512, 6) void k_fused(
      const u16* __restrict__ xT,              // [4][16384][128] X-format
      const u32* __restrict__ hK,              // [66][5][16384]  u32 (k-pair, X-fmt)
      const int* __restrict__ nb,              // [9][16384]
      const u16* __restrict__ Vt,              // [128][8448]     bf16
      const float* __restrict__ bias,
      float* __restrict__ out){
  __shared__ __align__(16) u16 A[2][2][32][136];  // dbuf x slab x row x j : 34,816 B
  __shared__ u32 hs[2][2][5][32];                 // dbuf x slab x kp x l  :  2,560 B
  __shared__ int pk[KNB][32];                     //                        1,152 B

  const int tid = threadIdx.x;
  const int r0  = blockIdx.x * 32;
  const int b   = r0 >> 14;
  const int l0  = r0 & (NS-1);

  if (tid < KNB*32){
    int k = tid >> 5, l = tid & 31;
    pk[k][l] = nb[k*NS + l0 + l];
  }
  WG_BARRIER();

  const int lq = tid >> 4;      // 0..31
  const int jc = tid & 15;      // j = jc*8

  // ---- h prefetch lanes: 320 threads each own one (slab,kp,l) slot ----
  const bool hact = tid < 320;
  const int  hs_  = tid / 160;          // slab (m parity)
  const int  hr_  = tid - hs_*160;
  const int  hkp_ = hr_ >> 5;           // kp 0..4
  const int  hl_  = hr_ & 31;           // l  0..31
  const u32* hKp  = hK + (((size_t)(5*hs_ + hkp_)) << 14) + l0 + hl_;
  const size_t HSTR = (size_t)10 << 14; // one mg step = 2 m-rows = 10 kp-rows
  u32 hra = 0, hrb = 0;
  if (hact){
    u32 h0 = hKp[0];          // mg=0
    hra = hKp[HSTR];          // mg=1
    hrb = hKp[2*HSTR];        // mg=2
    hs[0][hs_][hkp_][hl_] = h0;
  }

  // ---- gather x rows, pack into k-pairs (mg-invariant, register resident) ----
  const char* xbB = (const char*)(xT + ((size_t)b << 21));
  u32 xp[5][8];
  #pragma unroll
  for (int kp = 0; kp < 4; ++kp){
    u16x8 ga = *(const u16x8*)(xbB + (((size_t)(u32)pk[2*kp  ][lq]) << 8) + (size_t)jc*16);
    u16x8 gb = *(const u16x8*)(xbB + (((size_t)(u32)pk[2*kp+1][lq]) << 8) + (size_t)jc*16);
    #pragma unroll
    for (int j = 0; j < 8; ++j) xp[kp][j] = (u32)ga[j] | ((u32)gb[j] << 16);
  }
  {
    u16x8 ga = *(const u16x8*)(xbB + (((size_t)(u32)pk[8][lq]) << 8) + (size_t)jc*16);
    #pragma unroll
    for (int j = 0; j < 8; ++j) xp[4][j] = (u32)ga[j];   // hi half = +0.0
  }

  // ---- wave identity ----
  const int lane  = tid & 63;
  const int w     = tid >> 6;   // 0..7
  const int iq    = w & 3;      // i0 = iq*32
  const int kh    = w >> 2;     // K-half within each 128-j slab
  const int ar    = lane & 15;
  const int klane = lane >> 4;

  floatx4 acc[2][2];            // [row-frag][i-frag]
  #pragma unroll
  for (int r = 0; r < 2; ++r)
    #pragma unroll
    for (int f = 0; f < 2; ++f)
      acc[r][f] = (floatx4){0.f,0.f,0.f,0.f};

  // B bases: two 16-i col-frags; kh*128 + klane*16 selects this wave's K-half chunk
  const char* VtB0 = (const char*)Vt + (size_t)(iq*32      + ar)*(QDIM*2) + (size_t)(kh*128 + klane*16);
  const char* VtB1 = (const char*)Vt + (size_t)(iq*32 + 16 + ar)*(QDIM*2) + (size_t)(kh*128 + klane*16);

  // ---- prefetch mg=0 B-frags ----
  bf16x8 bv[2][4];              // [i-frag][mm*2+kt]
  #pragma unroll
  for (int mm = 0; mm < 2; ++mm)
    #pragma unroll
    for (int kt = 0; kt < 2; ++kt){
      bv[0][mm*2+kt] = *(const bf16x8*)(VtB0 + mm*256 + kt*64);
      bv[1][mm*2+kt] = *(const bf16x8*)(VtB1 + mm*256 + kt*64);
    }

  WG_BARRIER();   // hs[0] visible

  for (int mg = 0; mg < 33; ++mg){
    const int pb = mg & 1;

    // ---- build both A slabs via k-pair dot2 ----
    float a2[2][8];
    #pragma unroll
    for (int s = 0; s < 2; ++s)
      #pragma unroll
      for (int j = 0; j < 8; ++j) a2[s][j] = 0.f;
    #pragma unroll
    for (int s = 0; s < 2; ++s){
      #pragma unroll
      for (int kp = 0; kp < 5; ++kp){
        u32 hp = hs[pb][s][kp][lq];              // 16-lane broadcast
        #pragma unroll
        for (int j = 0; j < 8; ++j)
          a2[s][j] = dot2x(xp[kp][j], hp, a2[s][j]);
      }
    }
    {
      uint4 q0, q1;
      q0.x = cvtpk2(a2[0][0], a2[0][1]); q0.y = cvtpk2(a2[0][2], a2[0][3]);
      q0.z = cvtpk2(a2[0][4], a2[0][5]); q0.w = cvtpk2(a2[0][6], a2[0][7]);
      q1.x = cvtpk2(a2[1][0], a2[1][1]); q1.y = cvtpk2(a2[1][2], a2[1][3]);
      q1.z = cvtpk2(a2[1][4], a2[1][5]); q1.w = cvtpk2(a2[1][6], a2[1][7]);
      *(uint4*)&A[pb][0][lq][jc*8] = q0;
      *(uint4*)&A[pb][1][lq][jc*8] = q1;
    }

    // ---- rotate h pipeline: publish mg+1, issue mg+3 ----
    if (hact){
      if (mg < 32) hs[pb^1][hs_][hkp_][hl_] = hra;
      hra = hrb;
      if (mg <= 29) hrb = hKp[(size_t)(mg+3)*HSTR];
    }

    WG_BARRIER();   // A[pb] + hs[pb^1] published; vmcnt NOT drained

    // ---- MFMA: 2 m-slabs x 2 K-iters (this wave's K-half), full frag reuse ----
    #pragma unroll
    for (int mm = 0; mm < 2; ++mm){
      const char* Ab = (const char*)&A[pb][mm][0][0] + kh*128 + klane*16;
      #pragma unroll
      for (int kt = 0; kt < 2; ++kt){
        bf16x8 av0 = *(const bf16x8*)(Ab + (     ar)*272 + kt*64);
        bf16x8 av1 = *(const bf16x8*)(Ab + (16 + ar)*272 + kt*64);
        acc[0][0] = __builtin_amdgcn_mfma_f32_16x16x32_bf16(av0, bv[0][mm*2+kt], acc[0][0], 0, 0, 0);
        acc[0][1] = __builtin_amdgcn_mfma_f32_16x16x32_bf16(av0, bv[1][mm*2+kt], acc[0][1], 0, 0, 0);
        acc[1][0] = __builtin_amdgcn_mfma_f32_16x16x32_bf16(av1, bv[0][mm*2+kt], acc[1][0], 0, 0, 0);
        acc[1][1] = __builtin_amdgcn_mfma_f32_16x16x32_bf16(av1, bv[1][mm*2+kt], acc[1][1], 0, 0, 0);
      }
    }

    // ---- prefetch next mg's B-frags (land during next build) ----
    if (mg < 32){
      const char* Vg0 = VtB0 + (size_t)(mg+1)*512;
      const char* Vg1 = VtB1 + (size_t)(mg+1)*512;
      #pragma unroll
      for (int mm = 0; mm < 2; ++mm)
        #pragma unroll
        for (int kt = 0; kt < 2; ++kt){
          bv[0][mm*2+kt] = *(const bf16x8*)(Vg0 + mm*256 + kt*64);
          bv[1][mm*2+kt] = *(const bf16x8*)(Vg1 + mm*256 + kt*64);
        }
    }
  }

  // ---- epilogue: reduce kh pairs via LDS (reuse A buffer), then store ----
  WG_BARRIER();                 // all MFMA A-reads drained before overwrite
  floatx4* red = (floatx4*)&A[0][0][0][0];   // 4 iq * 64 lanes * 4 frags = 16 KB
  if (kh == 1){
    floatx4* dst = red + (((size_t)iq*64 + lane) << 2);
    dst[0] = acc[0][0]; dst[1] = acc[0][1]; dst[2] = acc[1][0]; dst[3] = acc[1][1];
  }
  WG_BARRIER();
  if (kh == 0){
    const floatx4* src = red + (((size_t)iq*64 + lane) << 2);
    acc[0][0] += src[0]; acc[0][1] += src[1];
    acc[1][0] += src[2]; acc[1][1] += src[3];
    float* ob = out + ((size_t)b << 21);
    #pragma unroll
    for (int rf = 0; rf < 2; ++rf){
      #pragma unroll
      for (int f = 0; f < 2; ++f){
        int i = iq*32 + f*16 + ar;
        float bi = bias[i];
        int l = l0 + rf*16 + klane*4;
        float4 v;
        v.x = acc[rf][f][0] + bi;
        v.y = acc[rf][f][1] + bi;
        v.z = acc[rf][f][2] + bi;
        v.w = acc[rf][f][3] + bi;
        *(float4*)(ob + ((size_t)i << 14) + l) = v;
      }
    }
  }
}

// ---------------- Naive zero-workspace fallback (correctness net) ----------------
__global__ __launch_bounds__(256) void k_naive(const float* __restrict__ x,
      const int* __restrict__ nb, const float* __restrict__ coords,
      const float* __restrict__ W1, const float* __restrict__ b1,
      const float* __restrict__ W2, const float* __restrict__ b2,
      const float* __restrict__ W3, const float* __restrict__ b3,
      const float* __restrict__ bias, float* __restrict__ out){
  __shared__ __align__(16) float hk[KNB][68];
  __shared__ int pk[KNB];
  __shared__ __align__(16) float xg[4][KNB][128];
  __shared__ __align__(16) float ul[128][66];
  int tid = threadIdx.x;
  int l = blockIdx.x;
  int lane = tid & 63, wid = tid >> 6;
  if (tid < KNB) pk[tid] = nb[tid*NS + l];
  for (int k = wid; k < KNB; k += 4){
    int pt = k*NS + l;
    float c0 = coords[2*pt], c1 = coords[2*pt+1];
    float z  = fmaf(c0, W1[lane], fmaf(c1, W1[64+lane], b1[lane]));
    float h1 = sinf(W0C*z);
    float a = b2[lane];
    for (int mp = 0; mp < 64; ++mp)
      a = fmaf(__shfl(h1, mp, 64), W2[mp*64+lane], a);
    hk[k][lane] = sinf(a);
    if (lane == 0){ hk[k][64] = 1.f; hk[k][65] = 0.f; }
  }
  __syncthreads();
  for (int idx = tid; idx < 4*KNB*128; idx += 256){
    int b = idx / (KNB*128);
    int r = idx - b*KNB*128;
    int k = r >> 7;
    int j = r & 127;
    xg[b][k][j] = x[((size_t)b*CIN + j)*NIN + pk[k]];
  }
  __syncthreads();
  for (int b = 0; b < 4; ++b){
    for (int idx = tid; idx < 128*65; idx += 256){
      int j = idx / 65, m = idx - j*65;
      float s = 0.f;
      for (int k = 0; k < KNB; ++k) s = fmaf(xg[b][k][j], hk[k][m], s);
      ul[j][m] = s;
    }
    __syncthreads();
    if (tid < 128){
      int i = tid;
      float v = bias[i];
      for (int j = 0; j < 128; ++j){
        const float* wcol = W3 + i*128 + j;
        for (int m = 0; m < 64; ++m)
          v = fmaf(ul[j][m], wcol[(size_t)m*16384], v);
        v = fmaf(ul[j][64], b3[i*128+j], v);
      }
      out[((size_t)b<<21) + ((size_t)i<<14) + l] = v;
    }
    __syncthreads();
  }
}

extern "C" void kernel_launch(void* const* d_in, const int* in_sizes, int n_in,
                              void* d_out, int out_size, void* d_ws, size_t ws_size,
                              hipStream_t stream) {
  const float* x      = (const float*)d_in[0];
  const int*   nb     = (const int*)  d_in[1];
  const float* coords = (const float*)d_in[2];
  const float* W1     = (const float*)d_in[3];
  const float* b1     = (const float*)d_in[4];
  const float* W2     = (const float*)d_in[5];
  const float* b2     = (const float*)d_in[6];
  const float* W3     = (const float*)d_in[7];
  const float* b3     = (const float*)d_in[8];
  const float* bias   = (const float*)d_in[9];
  float* out = (float*)d_out;

  const size_t VT_BYTES = (size_t)COUT*QDIM*2;        //  2,162,688
  const size_t HK_BYTES = (size_t)MCH*5*NS*4;         // 21,626,880
  const size_t XT_BYTES = (size_t)4*NIN*CIN*2;        // 16,777,216
  const size_t FIXED    = VT_BYTES + HK_BYTES + XT_BYTES;  // ~40.6 MB

  if (ws_size >= FIXED) {
    char* ws = (char*)d_ws;
    unsigned short* Vt = (unsigned short*)ws;
    u32*            hK = (u32*)(ws + VT_BYTES);
    unsigned short* xT = (unsigned short*)(ws + VT_BYTES + HK_BYTES);

    k_prep<<<PREP_K1H + PREP_KTR + PREP_K0, 1024, 0, stream>>>(
        coords, W1, b1, W2, b2, x, W3, b3, hK, xT, Vt);
    k_fused<<<(4*NS)/32, 512, 0, stream>>>(xT, hK, nb, Vt, bias, out);
  } else {
    k_naive<<<NS, 256, 0, stream>>>(x, nb, coords, W1, b1, W2, b2, W3, b3, bias, out);
  }
  (void)in_sizes; (void)n_in; (void)out_size;
}

// Round 12
// 682.840 us; speedup vs baseline: 3.2569x; 3.2569x over previous
//
#include <hip/hip_runtime.h>
#include <hip/hip_fp16.h>

#define NS   16384
#define NIN  16384
#define CIN  128
#define COUT 128
#define KNB  9
#define MCH  66              // 64 MLP channels + 1 (b3 ones) + 1 zero pad
#define QDIM (CIN*MCH)       // 8448, q = m*128 + j (j-fastest)
#define W0C  30.0f

typedef __bf16 bf16;
typedef bf16  bf16x8  __attribute__((ext_vector_type(8)));
typedef _Float16 f16;
typedef unsigned short u16;
typedef u16   u16x8   __attribute__((ext_vector_type(8)));
typedef float floatx4 __attribute__((ext_vector_type(4)));
typedef unsigned int u32;

__device__ inline u16 f2bf(float f){
  u32 u = __float_as_uint(f);
  u += 0x7fffu + ((u >> 16) & 1u);   // round-to-nearest-even
  return (u16)(u >> 16);
}
__device__ inline float bf2f(u16 s){
  return __uint_as_float((u32)s << 16);
}
__device__ inline u16 f2h(float f){
  f16 h = (f16)f; return __builtin_bit_cast(u16, h);
}
// 1-instr packed f32->2xbf16 (RNE), gfx950-verified instruction
__device__ inline u32 cvtpk2(float lo, float hi){
  u32 r; asm("v_cvt_pk_bf16_f32 %0, %1, %2" : "=v"(r) : "v"(lo), "v"(hi)); return r;
}

// ---- X-format (build operands xT, hK) is f16: the k-pair accumulate uses
// __hfma2 -> v_pk_fma_f16 (guaranteed HIP intrinsic; r10's __has_builtin dot2
// probe never engaged — counters were bit-identical to the bf16 fallback).
// f16 has MORE mantissa than bf16 for unit-scale data; accumulation error
// (~2^-11 over 5 terms) is far below A's bf16 storage rounding. Vt stays bf16.
#define F2X(f)  f2h(f)
#define X_ONE   0x3C00u

// barrier that orders LDS only — does NOT drain vmcnt, so global prefetches
// stay in flight across it (exact form used by the five-times-verified k_fused)
#define WG_BARRIER() do { \
  asm volatile("s_waitcnt lgkmcnt(0)" ::: "memory"); \
  __builtin_amdgcn_s_barrier(); \
} while (0)

// ---------------- K_prep: grid-partitioned fusion of k1h | k_tr | k0_vt ----------
#define PREP_K1H  (NS/32)                 // 512
#define PREP_KTR  2048                    // 8192 tiles / 4 per block
#define PREP_K0   ((COUT*QDIM + 1023)/1024)  // 1056
__global__ __launch_bounds__(1024) void k_prep(
      const float* __restrict__ coords,
      const float* __restrict__ W1, const float* __restrict__ b1,
      const float* __restrict__ W2, const float* __restrict__ b2,
      const float* __restrict__ x,
      const float* __restrict__ W3, const float* __restrict__ b3,
      u32* __restrict__ hK, u16* __restrict__ xT, u16* __restrict__ Vt){
  __shared__ u16 sh[KNB][32][66];              // 38,016 B (k1h role)
  __shared__ __align__(16) float tfl[4][32][33]; // 16,896 B (k_tr role)
  const int bid = blockIdx.x;
  const int tid = threadIdx.x;

  if (bid < PREP_K1H){
    // ---------------- k1h role ----------------
    const int lane = tid & 63;
    const int w    = tid >> 6;         // 0..15
    const int l0   = bid*32;
    for (int e = w; e < KNB*32; e += 16){
      int k = e >> 5, l = e & 31;
      int pt = (k << 14) + l0 + l;
      float c0 = coords[2*pt], c1 = coords[2*pt+1];
      float z  = fmaf(c0, W1[lane], fmaf(c1, W1[64+lane], b1[lane]));
      float h1 = sinf(W0C * z);
      float acc = b2[lane];
      #pragma unroll
      for (int mp = 0; mp < 64; ++mp)
        acc = fmaf(__shfl(h1, mp, 64), W2[mp*64 + lane], acc);
      sh[k][l][lane] = F2X(sinf(acc));
      if (lane == 0){ sh[k][l][64] = X_ONE; sh[k][l][65] = 0; }  // 1.0, 0.0
    }
    __syncthreads();
    for (int e = tid; e < 66*5*32; e += 1024){
      int m  = e / 160;
      int r  = e - m*160;
      int kp = r >> 5;
      int l  = r & 31;
      u32 lo = sh[2*kp][l][m];
      u32 hi = (kp < 4) ? (u32)sh[2*kp+1][l][m] : 0u;
      hK[(((size_t)m*5 + kp) << 14) + l0 + l] = lo | (hi << 16);
    }
  } else if (bid < PREP_K1H + PREP_KTR){
    // ---------------- k_tr role: 4 tiles of 32x32 per block ----------------
    const int sub = tid >> 8;          // 0..3 : which tile
    const int tx  = tid & 31;
    const int ty  = (tid >> 5) & 7;
    const int t   = (bid - PREP_K1H)*4 + sub;   // 0..8191
    const int p0  = (t & 511) * 32;             // NIN/32 = 512
    const int j0  = ((t >> 9) & 3) * 32;        // CIN/32 = 4
    const int b   = t >> 11;                    // 4
    const float* xb  = x  + (size_t)b*CIN*NIN;
    u16*         xTb = xT + (size_t)b*NIN*CIN;
    #pragma unroll
    for (int n = 0; n < 4; ++n)
      tfl[sub][ty+8*n][tx] = xb[(size_t)(j0+ty+8*n)*NIN + p0+tx];
    __syncthreads();
    #pragma unroll
    for (int n = 0; n < 4; ++n)
      xTb[(size_t)(p0+ty+8*n)*CIN + j0+tx] = F2X(tfl[sub][tx][ty+8*n]);
  } else {
    // ---------------- k0_vt role (bf16 — feeds MFMA B directly) ----------------
    int idx = (bid - PREP_K1H - PREP_KTR)*1024 + tid;
    if (idx < COUT*QDIM){
      int i = idx / QDIM;
      int q = idx - i*QDIM;
      int m = q >> 7;
      int j = q & 127;
      float v = 0.f;
      if (m < 64)       v = W3[m*16384 + i*128 + j];
      else if (m == 64) v = b3[i*128 + j];
      Vt[idx] = f2bf(v);
    }
  }
}

// ---------------- K_fused: r3-verified structure; build via v_pk_fma_f16 ---------
// block: 32 rows (one b) x 128 i, 512 threads (8 waves), (512,4) — r11's (512,6)
// spilled catastrophically (VGPR 40 + 9.2 GB scratch, 2062 us): register wall
// is structural, occupancy axis closed. This round cuts the largest busy pipe
// (VALU 24.7% = the bf16 unpack-fmaf fallback) via packed-f16 fma: ~320 ->
// ~140 VALU/thread/mg, guaranteed codegen. All else identical to r3/r8.
__global__ __launch_bounds__(512, 4) void k_fused(
      const u16* __restrict__ xT,              // [4][16384][128] f16
      const u32* __restrict__ hK,              // [66][5][16384]  u32 (f16 k-pair)
      const int* __restrict__ nb,              // [9][16384]
      const u16* __restrict__ Vt,              // [128][8448]     bf16
      const float* __restrict__ bias,
      float* __restrict__ out){
  __shared__ __align__(16) u16 A[2][2][32][136];  // dbuf x slab x row x j : 34,816 B
  __shared__ u32 hs[2][2][5][32];                 // dbuf x slab x kp x l  :  2,560 B
  __shared__ int pk[KNB][32];                     //                        1,152 B

  const int tid = threadIdx.x;
  const int r0  = blockIdx.x * 32;
  const int b   = r0 >> 14;
  const int l0  = r0 & (NS-1);

  if (tid < KNB*32){
    int k = tid >> 5, l = tid & 31;
    pk[k][l] = nb[k*NS + l0 + l];
  }
  WG_BARRIER();

  const int lq = tid >> 4;      // 0..31
  const int jc = tid & 15;      // j = jc*8

  // ---- h prefetch lanes: 320 threads each own one (slab,kp,l) slot ----
  const bool hact = tid < 320;
  const int  hs_  = tid / 160;          // slab (m parity)
  const int  hr_  = tid - hs_*160;
  const int  hkp_ = hr_ >> 5;           // kp 0..4
  const int  hl_  = hr_ & 31;           // l  0..31
  const u32* hKp  = hK + (((size_t)(5*hs_ + hkp_)) << 14) + l0 + hl_;
  const size_t HSTR = (size_t)10 << 14; // one mg step = 2 m-rows = 10 kp-rows
  u32 hra = 0, hrb = 0;
  if (hact){
    u32 h0 = hKp[0];          // mg=0
    hra = hKp[HSTR];          // mg=1
    hrb = hKp[2*HSTR];        // mg=2
    hs[0][hs_][hkp_][hl_] = h0;
  }

  // ---- gather x rows, pack into k-pairs (mg-invariant, register resident) ----
  const char* xbB = (const char*)(xT + ((size_t)b << 21));
  u32 xp[5][8];
  #pragma unroll
  for (int kp = 0; kp < 4; ++kp){
    u16x8 ga = *(const u16x8*)(xbB + (((size_t)(u32)pk[2*kp  ][lq]) << 8) + (size_t)jc*16);
    u16x8 gb = *(const u16x8*)(xbB + (((size_t)(u32)pk[2*kp+1][lq]) << 8) + (size_t)jc*16);
    #pragma unroll
    for (int j = 0; j < 8; ++j) xp[kp][j] = (u32)ga[j] | ((u32)gb[j] << 16);
  }
  {
    u16x8 ga = *(const u16x8*)(xbB + (((size_t)(u32)pk[8][lq]) << 8) + (size_t)jc*16);
    #pragma unroll
    for (int j = 0; j < 8; ++j) xp[4][j] = (u32)ga[j];   // hi half = +0.0 f16
  }

  // ---- wave identity ----
  const int lane  = tid & 63;
  const int w     = tid >> 6;   // 0..7
  const int iq    = w & 3;      // i0 = iq*32
  const int kh    = w >> 2;     // K-half within each 128-j slab
  const int ar    = lane & 15;
  const int klane = lane >> 4;

  floatx4 acc[2][2];            // [row-frag][i-frag]
  #pragma unroll
  for (int r = 0; r < 2; ++r)
    #pragma unroll
    for (int f = 0; f < 2; ++f)
      acc[r][f] = (floatx4){0.f,0.f,0.f,0.f};

  // B bases: two 16-i col-frags; kh*128 + klane*16 selects this wave's K-half chunk
  const char* VtB0 = (const char*)Vt + (size_t)(iq*32      + ar)*(QDIM*2) + (size_t)(kh*128 + klane*16);
  const char* VtB1 = (const char*)Vt + (size_t)(iq*32 + 16 + ar)*(QDIM*2) + (size_t)(kh*128 + klane*16);

  // ---- prefetch mg=0 B-frags ----
  bf16x8 bv[2][4];              // [i-frag][mm*2+kt]
  #pragma unroll
  for (int mm = 0; mm < 2; ++mm)
    #pragma unroll
    for (int kt = 0; kt < 2; ++kt){
      bv[0][mm*2+kt] = *(const bf16x8*)(VtB0 + mm*256 + kt*64);
      bv[1][mm*2+kt] = *(const bf16x8*)(VtB1 + mm*256 + kt*64);
    }

  WG_BARRIER();   // hs[0] visible

  for (int mg = 0; mg < 33; ++mg){
    const int pb = mg & 1;

    // ---- build both A slabs via packed f16 fma (v_pk_fma_f16, 1 instr/k-pair) ----
    __half2 ac2[2][8];
    #pragma unroll
    for (int s = 0; s < 2; ++s)
      #pragma unroll
      for (int j = 0; j < 8; ++j) ac2[s][j] = __builtin_bit_cast(__half2, 0u);
    #pragma unroll
    for (int s = 0; s < 2; ++s){
      #pragma unroll
      for (int kp = 0; kp < 5; ++kp){
        __half2 hp = __builtin_bit_cast(__half2, hs[pb][s][kp][lq]);  // 16-lane bcast
        #pragma unroll
        for (int j = 0; j < 8; ++j)
          ac2[s][j] = __hfma2(__builtin_bit_cast(__half2, xp[kp][j]), hp, ac2[s][j]);
      }
    }
    {
      float a2[2][8];
      #pragma unroll
      for (int s = 0; s < 2; ++s)
        #pragma unroll
        for (int j = 0; j < 8; ++j)
          a2[s][j] = __low2float(ac2[s][j]) + __high2float(ac2[s][j]);
      uint4 q0, q1;
      q0.x = cvtpk2(a2[0][0], a2[0][1]); q0.y = cvtpk2(a2[0][2], a2[0][3]);
      q0.z = cvtpk2(a2[0][4], a2[0][5]); q0.w = cvtpk2(a2[0][6], a2[0][7]);
      q1.x = cvtpk2(a2[1][0], a2[1][1]); q1.y = cvtpk2(a2[1][2], a2[1][3]);
      q1.z = cvtpk2(a2[1][4], a2[1][5]); q1.w = cvtpk2(a2[1][6], a2[1][7]);
      *(uint4*)&A[pb][0][lq][jc*8] = q0;
      *(uint4*)&A[pb][1][lq][jc*8] = q1;
    }

    // ---- rotate h pipeline: publish mg+1, issue mg+3 ----
    if (hact){
      if (mg < 32) hs[pb^1][hs_][hkp_][hl_] = hra;
      hra = hrb;
      if (mg <= 29) hrb = hKp[(size_t)(mg+3)*HSTR];
    }

    WG_BARRIER();   // A[pb] + hs[pb^1] published; vmcnt NOT drained

    // ---- MFMA: 2 m-slabs x 2 K-iters (this wave's K-half), full frag reuse ----
    #pragma unroll
    for (int mm = 0; mm < 2; ++mm){
      const char* Ab = (const char*)&A[pb][mm][0][0] + kh*128 + klane*16;
      #pragma unroll
      for (int kt = 0; kt < 2; ++kt){
        bf16x8 av0 = *(const bf16x8*)(Ab + (     ar)*272 + kt*64);
        bf16x8 av1 = *(const bf16x8*)(Ab + (16 + ar)*272 + kt*64);
        acc[0][0] = __builtin_amdgcn_mfma_f32_16x16x32_bf16(av0, bv[0][mm*2+kt], acc[0][0], 0, 0, 0);
        acc[0][1] = __builtin_amdgcn_mfma_f32_16x16x32_bf16(av0, bv[1][mm*2+kt], acc[0][1], 0, 0, 0);
        acc[1][0] = __builtin_amdgcn_mfma_f32_16x16x32_bf16(av1, bv[0][mm*2+kt], acc[1][0], 0, 0, 0);
        acc[1][1] = __builtin_amdgcn_mfma_f32_16x16x32_bf16(av1, bv[1][mm*2+kt], acc[1][1], 0, 0, 0);
      }
    }

    // ---- prefetch next mg's B-frags (land during next build) ----
    if (mg < 32){
      const char* Vg0 = VtB0 + (size_t)(mg+1)*512;
      const char* Vg1 = VtB1 + (size_t)(mg+1)*512;
      #pragma unroll
      for (int mm = 0; mm < 2; ++mm)
        #pragma unroll
        for (int kt = 0; kt < 2; ++kt){
          bv[0][mm*2+kt] = *(const bf16x8*)(Vg0 + mm*256 + kt*64);
          bv[1][mm*2+kt] = *(const bf16x8*)(Vg1 + mm*256 + kt*64);
        }
    }
  }

  // ---- epilogue: reduce kh pairs via LDS (reuse A buffer), then store ----
  WG_BARRIER();                 // all MFMA A-reads drained before overwrite
  floatx4* red = (floatx4*)&A[0][0][0][0];   // 4 iq * 64 lanes * 4 frags = 16 KB
  if (kh == 1){
    floatx4* dst = red + (((size_t)iq*64 + lane) << 2);
    dst[0] = acc[0][0]; dst[1] = acc[0][1]; dst[2] = acc[1][0]; dst[3] = acc[1][1];
  }
  WG_BARRIER();
  if (kh == 0){
    const floatx4* src = red + (((size_t)iq*64 + lane) << 2);
    acc[0][0] += src[0]; acc[0][1] += src[1];
    acc[1][0] += src[2]; acc[1][1] += src[3];
    float* ob = out + ((size_t)b << 21);
    #pragma unroll
    for (int rf = 0; rf < 2; ++rf){
      #pragma unroll
      for (int f = 0; f < 2; ++f){
        int i = iq*32 + f*16 + ar;
        float bi = bias[i];
        int l = l0 + rf*16 + klane*4;
        float4 v;
        v.x = acc[rf][f][0] + bi;
        v.y = acc[rf][f][1] + bi;
        v.z = acc[rf][f][2] + bi;
        v.w = acc[rf][f][3] + bi;
        *(float4*)(ob + ((size_t)i << 14) + l) = v;
      }
    }
  }
}

// ---------------- Naive zero-workspace fallback (correctness net) ----------------
__global__ __launch_bounds__(256) void k_naive(const float* __restrict__ x,
      const int* __restrict__ nb, const float* __restrict__ coords,
      const float* __restrict__ W1, const float* __restrict__ b1,
      const float* __restrict__ W2, const float* __restrict__ b2,
      const float* __restrict__ W3, const float* __restrict__ b3,
      const float* __restrict__ bias, float* __restrict__ out){
  __shared__ __align__(16) float hk[KNB][68];
  __shared__ int pk[KNB];
  __shared__ __align__(16) float xg[4][KNB][128];
  __shared__ __align__(16) float ul[128][66];
  int tid = threadIdx.x;
  int l = blockIdx.x;
  int lane = tid & 63, wid = tid >> 6;
  if (tid < KNB) pk[tid] = nb[tid*NS + l];
  for (int k = wid; k < KNB; k += 4){
    int pt = k*NS + l;
    float c0 = coords[2*pt], c1 = coords[2*pt+1];
    float z  = fmaf(c0, W1[lane], fmaf(c1, W1[64+lane], b1[lane]));
    float h1 = sinf(W0C*z);
    float a = b2[lane];
    for (int mp = 0; mp < 64; ++mp)
      a = fmaf(__shfl(h1, mp, 64), W2[mp*64+lane], a);
    hk[k][lane] = sinf(a);
    if (lane == 0){ hk[k][64] = 1.f; hk[k][65] = 0.f; }
  }
  __syncthreads();
  for (int idx = tid; idx < 4*KNB*128; idx += 256){
    int b = idx / (KNB*128);
    int r = idx - b*KNB*128;
    int k = r >> 7;
    int j = r & 127;
    xg[b][k][j] = x[((size_t)b*CIN + j)*NIN + pk[k]];
  }
  __syncthreads();
  for (int b = 0; b < 4; ++b){
    for (int idx = tid; idx < 128*65; idx += 256){
      int j = idx / 65, m = idx - j*65;
      float s = 0.f;
      for (int k = 0; k < KNB; ++k) s = fmaf(xg[b][k][j], hk[k][m], s);
      ul[j][m] = s;
    }
    __syncthreads();
    if (tid < 128){
      int i = tid;
      float v = bias[i];
      for (int j = 0; j < 128; ++j){
        const float* wcol = W3 + i*128 + j;
        for (int m = 0; m < 64; ++m)
          v = fmaf(ul[j][m], wcol[(size_t)m*16384], v);
        v = fmaf(ul[j][64], b3[i*128+j], v);
      }
      out[((size_t)b<<21) + ((size_t)i<<14) + l] = v;
    }
    __syncthreads();
  }
}

extern "C" void kernel_launch(void* const* d_in, const int* in_sizes, int n_in,
                              void* d_out, int out_size, void* d_ws, size_t ws_size,
                              hipStream_t stream) {
  const float* x      = (const float*)d_in[0];
  const int*   nb     = (const int*)  d_in[1];
  const float* coords = (const float*)d_in[2];
  const float* W1     = (const float*)d_in[3];
  const float* b1     = (const float*)d_in[4];
  const float* W2     = (const float*)d_in[5];
  const float* b2     = (const float*)d_in[6];
  const float* W3     = (const float*)d_in[7];
  const float* b3     = (const float*)d_in[8];
  const float* bias   = (const float*)d_in[9];
  float* out = (float*)d_out;

  const size_t VT_BYTES = (size_t)COUT*QDIM*2;        //  2,162,688
  const size_t HK_BYTES = (size_t)MCH*5*NS*4;         // 21,626,880
  const size_t XT_BYTES = (size_t)4*NIN*CIN*2;        // 16,777,216
  const size_t FIXED    = VT_BYTES + HK_BYTES + XT_BYTES;  // ~40.6 MB

  if (ws_size >= FIXED) {
    char* ws = (char*)d_ws;
    unsigned short* Vt = (unsigned short*)ws;
    u32*            hK = (u32*)(ws + VT_BYTES);
    unsigned short* xT = (unsigned short*)(ws + VT_BYTES + HK_BYTES);

    k_prep<<<PREP_K1H + PREP_KTR + PREP_K0, 1024, 0, stream>>>(
        coords, W1, b1, W2, b2, x, W3, b3, hK, xT, Vt);
    k_fused<<<(4*NS)/32, 512, 0, stream>>>(xT, hK, nb, Vt, bias, out);
  } else {
    k_naive<<<NS, 256, 0, stream>>>(x, nb, coords, W1, b1, W2, b2, W3, b3, bias, out);
  }
  (void)in_sizes; (void)n_in; (void)out_size;
}